// Round 20
// baseline (68.129 us; speedup 1.0000x reference)
//
#include <hip/hip_runtime.h>

#define NEG_SLOPE 0.1f

typedef _Float16 h4_t __attribute__((ext_vector_type(4)));
typedef _Float16 h8_t __attribute__((ext_vector_type(8)));
typedef float f32x4 __attribute__((ext_vector_type(4)));

__device__ __forceinline__ unsigned lds_off(const void* p) {
    return (unsigned)(unsigned long long)p;
}

__device__ __forceinline__ void lgkm0() {
    asm volatile("s_waitcnt lgkmcnt(0)" ::: "memory");
    __builtin_amdgcn_sched_barrier(0);        // rule #18
}

__device__ __forceinline__ h4_t tr16(unsigned addr) {
    h4_t d;
    asm volatile("ds_read_b64_tr_b16 %0, %1" : "=v"(d) : "v"(addr) : "memory");
    return d;
}

#define RCH 4

// ---------------------------------------------------------------------------
// K0 prep: W2T + wpack + WfT=(Wpca@W1)^T fp16 + bfused + out init.
// blocks: [0,1024) W2T | [1024,3328) wpack | [3328,4352) WfT |
//         4352 bfused | [4353,4369) out-init.   (x16 branch removed — K1
//         now consumes x fp32 directly with in-register conversion.)
// ---------------------------------------------------------------------------
__global__ __launch_bounds__(256) void prep2(const float* __restrict__ W2,
                                             const float* __restrict__ W1,
                                             const float* __restrict__ Wpca,
                                             const float* __restrict__ bpca,
                                             const float* __restrict__ b1,
                                             const float* __restrict__ a1W,
                                             const float* __restrict__ a2W,
                                             const float* __restrict__ Wp2,
                                             const float* __restrict__ bp2,
                                             const float* __restrict__ Wl,
                                             const float* __restrict__ bl,
                                             _Float16* __restrict__ W2T,
                                             _Float16* __restrict__ wpack,
                                             _Float16* __restrict__ WfT,
                                             float* __restrict__ bfused,
                                             float* __restrict__ out)
{
    __shared__ alignas(16) char smem[17408];
    const int b   = blockIdx.x;
    const int tid = threadIdx.x;

    if (b < 1024) {                         // W2T[n][k] = fp16 W2[k][n]
        float (*tile)[33] = reinterpret_cast<float(*)[33]>(smem);
        const int n0 = (b & 31) * 32, k0 = (b >> 5) * 32;
        const int r = tid >> 3, c4 = (tid & 7) * 4;
        float4 v = *reinterpret_cast<const float4*>(&W2[(size_t)(k0 + r) * 1024 + n0 + c4]);
        tile[r][c4 + 0] = v.x; tile[r][c4 + 1] = v.y;
        tile[r][c4 + 2] = v.z; tile[r][c4 + 3] = v.w;
        __syncthreads();
        h4_t o;
        o[0] = (_Float16)tile[c4 + 0][r]; o[1] = (_Float16)tile[c4 + 1][r];
        o[2] = (_Float16)tile[c4 + 2][r]; o[3] = (_Float16)tile[c4 + 3][r];
        *reinterpret_cast<h4_t*>(&W2T[(size_t)(n0 + r) * 1024 + k0 + c4]) = o;
    } else if (b < 3328) {                  // pack tail weights (K=32 B-frag)
        const int idx = (b - 1024) * 256 + tid;
        if (idx < 589824) {
            const int r = idx / 9216, qq = idx % 9216;
            float v;
            if (qq < 1024) {
                int nt = qq >> 8, rem = qq & 255, l = rem >> 2, j = rem & 3;
                int n = nt * 16 + (l & 15), k = (l >> 4) * 4 + j;
                v = a1W[(size_t)r * 1024 + k * 64 + n];
            } else if (qq < 5120) {
                int p = qq - 1024, kt = p >> 11, u = p & 2047, nt = u >> 9, s = u & 511,
                    l = s >> 3, j = s & 7;
                int n = nt * 16 + (l & 15), k = kt * 32 + (l >> 4) * 8 + j;
                v = a2W[(size_t)r * 4096 + k * 64 + n];
            } else {
                int p = qq - 5120, kt = p >> 11, u = p & 2047, nt = u >> 9, s = u & 511,
                    l = s >> 3, j = s & 7;
                int n = nt * 16 + (l & 15), k = kt * 32 + (l >> 4) * 8 + j;
                v = Wp2[((size_t)r * 64 + k) * 64 + n];
            }
            wpack[idx] = (_Float16)v;
        }
    } else if (b < 4352) {                  // WfT[n][k] = fp16 sum_j Wpca[k][j]W1[j][n]
        float (*Ws)[65]  = reinterpret_cast<float(*)[65]>(smem);          // Wpca rows
        float (*W1s)[33] = reinterpret_cast<float(*)[33]>(smem + 8448);   // W1 cols
        const int b3 = b - 3328;
        const int n0 = (b3 & 31) * 32, k0 = (b3 >> 5) * 32;
        {
            const int r  = tid >> 3;            // 0..31
            const int j0 = (tid & 7) * 8;
            float4 v0 = *reinterpret_cast<const float4*>(&Wpca[(size_t)(k0 + r) * 64 + j0]);
            float4 v1 = *reinterpret_cast<const float4*>(&Wpca[(size_t)(k0 + r) * 64 + j0 + 4]);
            Ws[r][j0 + 0] = v0.x; Ws[r][j0 + 1] = v0.y; Ws[r][j0 + 2] = v0.z; Ws[r][j0 + 3] = v0.w;
            Ws[r][j0 + 4] = v1.x; Ws[r][j0 + 5] = v1.y; Ws[r][j0 + 6] = v1.z; Ws[r][j0 + 7] = v1.w;
            const int j  = tid >> 2;            // 0..63
            const int nq = (tid & 3) * 8;
            float4 w0 = *reinterpret_cast<const float4*>(&W1[(size_t)j * 1024 + n0 + nq]);
            float4 w1 = *reinterpret_cast<const float4*>(&W1[(size_t)j * 1024 + n0 + nq + 4]);
            W1s[j][nq + 0] = w0.x; W1s[j][nq + 1] = w0.y; W1s[j][nq + 2] = w0.z; W1s[j][nq + 3] = w0.w;
            W1s[j][nq + 4] = w1.x; W1s[j][nq + 5] = w1.y; W1s[j][nq + 6] = w1.z; W1s[j][nq + 7] = w1.w;
        }
        __syncthreads();
        const int nl = tid >> 3;            // 0..31
        const int kq = (tid & 7) * 4;
        float acc[4] = {0.f, 0.f, 0.f, 0.f};
#pragma unroll
        for (int j = 0; j < 64; ++j) {
            float wv = W1s[j][nl];
#pragma unroll
            for (int kk = 0; kk < 4; ++kk)
                acc[kk] = fmaf(Ws[kq + kk][j], wv, acc[kk]);
        }
        h4_t pk;
        pk[0] = (_Float16)acc[0]; pk[1] = (_Float16)acc[1];
        pk[2] = (_Float16)acc[2]; pk[3] = (_Float16)acc[3];
        *reinterpret_cast<h4_t*>(&WfT[(size_t)(n0 + nl) * 1024 + k0 + kq]) = pk;
    } else if (b == 4352) {                 // bfused[n] = b1[n] + sum_j bpca[j]W1[j][n]
        const int n = tid * 4;
        float a0 = b1[n], a1v = b1[n + 1], a2v = b1[n + 2], a3 = b1[n + 3];
#pragma unroll
        for (int j = 0; j < 64; ++j) {
            float bp = bpca[j];
            a0  = fmaf(bp, W1[(size_t)j * 1024 + n + 0], a0);
            a1v = fmaf(bp, W1[(size_t)j * 1024 + n + 1], a1v);
            a2v = fmaf(bp, W1[(size_t)j * 1024 + n + 2], a2v);
            a3  = fmaf(bp, W1[(size_t)j * 1024 + n + 3], a3);
        }
        float4 o; o.x = a0; o.y = a1v; o.z = a2v; o.w = a3;
        *reinterpret_cast<float4*>(&bfused[n]) = o;
    } else {                                // out init with constant term
        const int idx = (b - 4353) * 256 + tid;
        float cst = bl[0];
#pragma unroll
        for (int f = 0; f < 64; ++f)
            cst += bp2[f] * Wl[f];
        out[idx] = cst;
    }
}

// ---------------------------------------------------------------------------
// K1: h1h = leaky(x @ Wf + bfused) — A consumed as fp32 with in-register
// fp16 conversion during staging (pre-swizzled source addr, linear ds_write,
// same XOR involution on reads). B unchanged (global_load_lds).
// ---------------------------------------------------------------------------
__global__ __launch_bounds__(256) void gemm_h1(const float* __restrict__ X,
                                               const _Float16* __restrict__ BT,
                                               const float* __restrict__ bias,
                                               _Float16* __restrict__ C)
{
    __shared__ alignas(16) _Float16 As[64 * 64];
    __shared__ alignas(16) _Float16 Bs[128 * 64];
    const int tid = threadIdx.x;
    const int l   = tid & 63;
    const int w   = tid >> 6;
    const int wm  = w >> 1;
    const int wn  = w & 1;
    const int bm0 = blockIdx.y * 64;
    const int bn0 = blockIdx.x * 128;
    const int fr  = l & 15;
    const int fg  = l >> 4;
    const int srow  = l >> 3;
    const int sslot = l & 7;

    f32x4 acc[2][4] = {};

    for (int k0 = 0; k0 < 1024; k0 += 64) {
#pragma unroll
        for (int i = 0; i < 2; ++i) {          // A: reg-staged fp32 -> fp16
            const int r0   = w * 16 + i * 8;
            const int rowA = r0 + srow;
            const int slot = sslot ^ (rowA & 7);
            const float* gx = &X[(size_t)(bm0 + rowA) * 1024 + k0 + slot * 8];
            float4 v0 = *reinterpret_cast<const float4*>(gx);
            float4 v1 = *reinterpret_cast<const float4*>(gx + 4);
            h8_t o;
            o[0] = (_Float16)v0.x; o[1] = (_Float16)v0.y;
            o[2] = (_Float16)v0.z; o[3] = (_Float16)v0.w;
            o[4] = (_Float16)v1.x; o[5] = (_Float16)v1.y;
            o[6] = (_Float16)v1.z; o[7] = (_Float16)v1.w;
            *reinterpret_cast<h8_t*>(&As[r0 * 64 + l * 8]) = o;
        }
#pragma unroll
        for (int i = 0; i < 4; ++i) {          // B: global_load_lds (unchanged)
            const int r0   = w * 32 + i * 8;
            const int rowB = r0 + srow;
            const int slot = sslot ^ (rowB & 7);
            __builtin_amdgcn_global_load_lds(
                (const __attribute__((address_space(1))) void*)&BT[(size_t)(bn0 + rowB) * 1024 + k0 + slot * 8],
                (__attribute__((address_space(3))) void*)&Bs[r0 * 64], 16, 0, 0);
        }
        __syncthreads();

#pragma unroll
        for (int ks = 0; ks < 2; ++ks) {
            h8_t af[2], bf[4];
#pragma unroll
            for (int mt = 0; mt < 2; ++mt) {
                int row = wm * 32 + mt * 16 + fr;
                int sg  = ks * 4 + fg;
                af[mt] = *reinterpret_cast<const h8_t*>(&As[row * 64 + ((sg ^ (row & 7)) << 3)]);
            }
#pragma unroll
            for (int nt = 0; nt < 4; ++nt) {
                int row = wn * 64 + nt * 16 + fr;
                int sg  = ks * 4 + fg;
                bf[nt] = *reinterpret_cast<const h8_t*>(&Bs[row * 64 + ((sg ^ (row & 7)) << 3)]);
            }
#pragma unroll
            for (int mt = 0; mt < 2; ++mt)
#pragma unroll
                for (int nt = 0; nt < 4; ++nt)
                    acc[mt][nt] = __builtin_amdgcn_mfma_f32_16x16x32_f16(af[mt], bf[nt],
                                                                         acc[mt][nt], 0, 0, 0);
        }
        __syncthreads();
    }

#pragma unroll
    for (int nt = 0; nt < 4; ++nt) {
        const int col = bn0 + wn * 64 + nt * 16 + fr;
        const float bv = bias[col];
#pragma unroll
        for (int mt = 0; mt < 2; ++mt)
#pragma unroll
            for (int rg = 0; rg < 4; ++rg) {
                const int row = bm0 + wm * 32 + mt * 16 + fg * 4 + rg;
                float v = acc[mt][nt][rg] + bv;
                C[(size_t)row * 1024 + col] = (_Float16)fmaxf(v, NEG_SLOPE * v);
            }
    }
}

// ---------------------------------------------------------------------------
// K2: h2t = pack(leaky(h1 @ W2 + b2)). (unchanged proven v2)
// ---------------------------------------------------------------------------
__global__ __launch_bounds__(256) void gemm_mfma_f16_v2(const _Float16* __restrict__ A,
                                                        const _Float16* __restrict__ BT,
                                                        const float* __restrict__ bias,
                                                        _Float16* __restrict__ h2t)
{
    __shared__ alignas(16) _Float16 As[64 * 64];
    __shared__ alignas(16) _Float16 Bs[128 * 64];
    const int tid = threadIdx.x;
    const int l   = tid & 63;
    const int w   = tid >> 6;
    const int wm  = w >> 1;
    const int wn  = w & 1;
    const int bm0 = blockIdx.y * 64;
    const int bn0 = blockIdx.x * 128;
    const int fr  = l & 15;
    const int fg  = l >> 4;
    const int srow  = l >> 3;
    const int sslot = l & 7;

    f32x4 acc[2][4] = {};

    for (int k0 = 0; k0 < 1024; k0 += 64) {
#pragma unroll
        for (int i = 0; i < 2; ++i) {
            const int r0   = w * 16 + i * 8;
            const int rowA = r0 + srow;
            const int slot = sslot ^ (rowA & 7);
            __builtin_amdgcn_global_load_lds(
                (const __attribute__((address_space(1))) void*)&A[(size_t)(bm0 + rowA) * 1024 + k0 + slot * 8],
                (__attribute__((address_space(3))) void*)&As[r0 * 64], 16, 0, 0);
        }
#pragma unroll
        for (int i = 0; i < 4; ++i) {
            const int r0   = w * 32 + i * 8;
            const int rowB = r0 + srow;
            const int slot = sslot ^ (rowB & 7);
            __builtin_amdgcn_global_load_lds(
                (const __attribute__((address_space(1))) void*)&BT[(size_t)(bn0 + rowB) * 1024 + k0 + slot * 8],
                (__attribute__((address_space(3))) void*)&Bs[r0 * 64], 16, 0, 0);
        }
        __syncthreads();

#pragma unroll
        for (int ks = 0; ks < 2; ++ks) {
            h8_t af[2], bf[4];
#pragma unroll
            for (int mt = 0; mt < 2; ++mt) {
                int row = wm * 32 + mt * 16 + fr;
                int sg  = ks * 4 + fg;
                af[mt] = *reinterpret_cast<const h8_t*>(&As[row * 64 + ((sg ^ (row & 7)) << 3)]);
            }
#pragma unroll
            for (int nt = 0; nt < 4; ++nt) {
                int row = wn * 64 + nt * 16 + fr;
                int sg  = ks * 4 + fg;
                bf[nt] = *reinterpret_cast<const h8_t*>(&Bs[row * 64 + ((sg ^ (row & 7)) << 3)]);
            }
#pragma unroll
            for (int mt = 0; mt < 2; ++mt)
#pragma unroll
                for (int nt = 0; nt < 4; ++nt)
                    acc[mt][nt] = __builtin_amdgcn_mfma_f32_16x16x32_f16(af[mt], bf[nt],
                                                                         acc[mt][nt], 0, 0, 0);
        }
        __syncthreads();
    }

    const int rblk0 = (bm0 >> 4) + wm * 2;
    const int cblk0 = (bn0 >> 4) + wn * 4;
#pragma unroll
    for (int nt = 0; nt < 4; ++nt) {
        const int col = bn0 + wn * 64 + nt * 16 + fr;
        const float bv = bias[col];
#pragma unroll
        for (int mt = 0; mt < 2; ++mt) {
            h4_t pk;
#pragma unroll
            for (int r = 0; r < 4; ++r) {
                float v = acc[mt][nt][r] + bv;
                pk[r] = (_Float16)fmaxf(v, NEG_SLOPE * v);
            }
            *reinterpret_cast<h4_t*>(
                &h2t[(((size_t)(cblk0 + nt) * 256 + rblk0 + mt) * 16 + fr) * 16 + fg * 4]) = pk;
        }
    }
}

// ---------------------------------------------------------------------------
// K3: fused additive chain v5b (unchanged from passing round 19).
// ---------------------------------------------------------------------------
__global__ __launch_bounds__(256) void fused_tail5b(const _Float16* __restrict__ h2t,
                                                    const _Float16* __restrict__ wpack,
                                                    const float* __restrict__ a1b,
                                                    const float* __restrict__ a1bias,
                                                    const float* __restrict__ a2b,
                                                    const float* __restrict__ a2bias,
                                                    const float* __restrict__ Wl,
                                                    float* __restrict__ out)
{
    __shared__ alignas(16) _Float16 stage[2][11264];  // 2 x 22KB
    __shared__ alignas(16) _Float16 act[4][2048];     // per-wave, 2 tiles (16KB)

    const int tid = threadIdx.x;
    const int l = tid & 63, w = tid >> 6;
    const int c = l & 15, q = l >> 4;
    const int row0  = blockIdx.x * 128;
    const int rbase = blockIdx.y * RCH;
    const float b1s = a1bias[0], b2s = a2bias[0];

    const unsigned trl   = l * 8;
    const unsigned abase = lds_off(&act[w][0]);

    float b1v[RCH][4], b2v[RCH][4];
#pragma unroll
    for (int rl = 0; rl < RCH; ++rl)
#pragma unroll
        for (int nt = 0; nt < 4; ++nt) {
            b1v[rl][nt] = a1b[(rbase + rl) * 64 + nt * 16 + c] + b1s;
            b2v[rl][nt] = a2b[(rbase + rl) * 64 + nt * 16 + c] + b2s;
        }
    float wlv[4];
#pragma unroll
    for (int nt = 0; nt < 4; ++nt) wlv[nt] = Wl[nt * 16 + c];

    auto STAGE = [&](int rl, int b) {
        const int r = rbase + rl;
        const _Float16* hsrc = h2t + ((size_t)r * 256 + blockIdx.x * 8) * 256;
        const _Float16* wsrc = wpack + (size_t)r * 9216;
#pragma unroll
        for (int i = 0; i < 6; ++i) {
            const int ch = i * 4 + w;
            if (ch < 22) {
                const _Float16* src = (ch < 4) ? (hsrc + ch * 512) : (wsrc + (ch - 4) * 512);
                __builtin_amdgcn_global_load_lds(
                    (const __attribute__((address_space(1))) void*)(src + l * 8),
                    (__attribute__((address_space(3))) void*)&stage[b][ch * 512], 16, 0, 0);
            }
        }
    };

    STAGE(0, 0);
    __syncthreads();

    f32x4 accT[2][4] = {};
    int cur = 0;

#pragma unroll
    for (int rl = 0; rl < RCH; ++rl) {
        if (rl + 1 < RCH) STAGE(rl + 1, cur ^ 1);

        const _Float16* sp = &stage[cur][0];
        const unsigned sbytes = lds_off(sp);

        // ---- phase A
        h4_t ha0 = tr16(sbytes + (unsigned)(w) * 512 + trl);
        h4_t ha1 = tr16(sbytes + (unsigned)(w + 4) * 512 + trl);
        lgkm0();
        f32x4 pa[2][4];
#pragma unroll
        for (int nt = 0; nt < 4; ++nt) {
            h4_t bf = *reinterpret_cast<const h4_t*>(&sp[2048 + nt * 256 + l * 4]);
            pa[0][nt] = __builtin_amdgcn_mfma_f32_16x16x16f16(ha0, bf, (f32x4){0.f,0.f,0.f,0.f}, 0, 0, 0);
            pa[1][nt] = __builtin_amdgcn_mfma_f32_16x16x16f16(ha1, bf, (f32x4){0.f,0.f,0.f,0.f}, 0, 0, 0);
        }
#pragma unroll
        for (int j = 0; j < 2; ++j)
#pragma unroll
            for (int nt = 0; nt < 4; ++nt) {
                h4_t pk;
#pragma unroll
                for (int rg = 0; rg < 4; ++rg) {
                    float v = pa[j][nt][rg] + b1v[rl][nt];
                    pk[rg] = (_Float16)fmaxf(v, NEG_SLOPE * v);
                }
                const int kk = nt * 16 + c;
                const int hh = (kk >> 2) & 1;
                const int kp = (kk & 3) | ((kk >> 3) << 2);
                *reinterpret_cast<h4_t*>(&act[w][j * 1024 + hh * 512 + kp * 16 + q * 4]) = pk;
            }
        lgkm0();

        // ---- phase B
        h8_t afB[2][2];
#pragma unroll
        for (int j = 0; j < 2; ++j)
#pragma unroll
            for (int kt = 0; kt < 2; ++kt) {
                h4_t lo = tr16(abase + (unsigned)(j * 2048 + kt * 512) + trl);
                h4_t hi = tr16(abase + (unsigned)(j * 2048 + 1024 + kt * 512) + trl);
                afB[j][kt] = __builtin_shufflevector(lo, hi, 0, 1, 2, 3, 4, 5, 6, 7);
            }
        lgkm0();
        f32x4 pb[2][4] = {};
#pragma unroll
        for (int kt = 0; kt < 2; ++kt)
#pragma unroll
            for (int nt = 0; nt < 4; ++nt) {
                h8_t bf = *reinterpret_cast<const h8_t*>(&sp[3072 + kt * 2048 + nt * 512 + l * 8]);
                pb[0][nt] = __builtin_amdgcn_mfma_f32_16x16x32_f16(afB[0][kt], bf, pb[0][nt], 0, 0, 0);
                pb[1][nt] = __builtin_amdgcn_mfma_f32_16x16x32_f16(afB[1][kt], bf, pb[1][nt], 0, 0, 0);
            }
#pragma unroll
        for (int j = 0; j < 2; ++j)
#pragma unroll
            for (int nt = 0; nt < 4; ++nt) {
                h4_t pk;
#pragma unroll
                for (int rg = 0; rg < 4; ++rg) {
                    float v = pb[j][nt][rg] + b2v[rl][nt];
                    pk[rg] = (_Float16)fmaxf(v, NEG_SLOPE * v);
                }
                const int kk = nt * 16 + c;
                const int hh = (kk >> 2) & 1;
                const int kp = (kk & 3) | ((kk >> 3) << 2);
                *reinterpret_cast<h4_t*>(&act[w][j * 1024 + hh * 512 + kp * 16 + q * 4]) = pk;
            }
        lgkm0();

        // ---- phase C
        h8_t afC[2][2];
#pragma unroll
        for (int j = 0; j < 2; ++j)
#pragma unroll
            for (int kt = 0; kt < 2; ++kt) {
                h4_t lo = tr16(abase + (unsigned)(j * 2048 + kt * 512) + trl);
                h4_t hi = tr16(abase + (unsigned)(j * 2048 + 1024 + kt * 512) + trl);
                afC[j][kt] = __builtin_shufflevector(lo, hi, 0, 1, 2, 3, 4, 5, 6, 7);
            }
        lgkm0();
#pragma unroll
        for (int kt = 0; kt < 2; ++kt)
#pragma unroll
            for (int nt = 0; nt < 4; ++nt) {
                h8_t bf = *reinterpret_cast<const h8_t*>(&sp[7168 + kt * 2048 + nt * 512 + l * 8]);
                accT[0][nt] = __builtin_amdgcn_mfma_f32_16x16x32_f16(afC[0][kt], bf, accT[0][nt], 0, 0, 0);
                accT[1][nt] = __builtin_amdgcn_mfma_f32_16x16x32_f16(afC[1][kt], bf, accT[1][nt], 0, 0, 0);
            }

        __syncthreads();
        cur ^= 1;
    }

    // ---- epilogue: per-row dot with Wl, lane-reduce, atomicAdd
#pragma unroll
    for (int j = 0; j < 2; ++j)
#pragma unroll
        for (int rg = 0; rg < 4; ++rg) {
            float s = accT[j][0][rg] * wlv[0] + accT[j][1][rg] * wlv[1] +
                      accT[j][2][rg] * wlv[2] + accT[j][3][rg] * wlv[3];
            s += __shfl_xor(s, 1);
            s += __shfl_xor(s, 2);
            s += __shfl_xor(s, 4);
            s += __shfl_xor(s, 8);
            if (c == 0) {
                const int row = row0 + (w + 4 * j) * 16 + q * 4 + rg;
                atomicAdd(&out[row], s);
            }
        }
}

// ---------------------------------------------------------------------------
extern "C" void kernel_launch(void* const* d_in, const int* in_sizes, int n_in,
                              void* d_out, int out_size, void* d_ws, size_t ws_size,
                              hipStream_t stream)
{
    const float* x      = (const float*)d_in[0];
    const float* Wpca   = (const float*)d_in[1];
    const float* bpca   = (const float*)d_in[2];
    const float* W1     = (const float*)d_in[3];
    const float* b1     = (const float*)d_in[4];
    const float* W2     = (const float*)d_in[5];
    const float* b2     = (const float*)d_in[6];
    const float* a1W    = (const float*)d_in[7];
    const float* a1b    = (const float*)d_in[8];
    const float* a1bias = (const float*)d_in[9];
    const float* a2W    = (const float*)d_in[10];
    const float* a2b    = (const float*)d_in[11];
    const float* a2bias = (const float*)d_in[12];
    const float* Wp2    = (const float*)d_in[13];
    const float* bp2    = (const float*)d_in[14];
    const float* Wl     = (const float*)d_in[15];
    const float* bl     = (const float*)d_in[16];
    float* out = (float*)d_out;

    // workspace layout (bytes) — fully disjoint:
    //   h1h [0,8M)  h2t [8M,16M)  W2T [16M,18M)  wpack [18M,19.13M)
    //   WfT [20M,22M)  bfused [22.5M,+4KB)
    char* wsb = (char*)d_ws;
    _Float16* h1h    = (_Float16*)(wsb);
    _Float16* h2t    = (_Float16*)(wsb + (8ull  << 20));
    _Float16* W2T    = (_Float16*)(wsb + (16ull << 20));
    _Float16* wpack  = (_Float16*)(wsb + (18ull << 20));
    _Float16* WfT    = (_Float16*)(wsb + (20ull << 20));
    float*    bfused = (float*)   (wsb + (22ull << 20) + (512ull << 10));

    // K0: prep (W2T || wpack || WfT || bfused || out-init)
    prep2<<<dim3(4369), 256, 0, stream>>>(W2, W1, Wpca, bpca, b1, a1W, a2W, Wp2,
                                          bp2, Wl, bl, W2T, wpack, WfT, bfused, out);
    // K1: h1 = leaky(x @ (Wpca@W1) + bfused) — x fp32 consumed directly
    gemm_h1<<<dim3(8, 64), 256, 0, stream>>>(x, WfT, bfused, h1h);
    // K2: h2 (packed) = leaky(h1 @ W2 + b2) via MFMA
    gemm_mfma_f16_v2<<<dim3(8, 64), 256, 0, stream>>>(h1h, W2T, b2, h2t);
    // K3: fused additive chain -> atomicAdd into out
    fused_tail5b<<<dim3(32, 16), 256, 0, stream>>>(h2t, wpack, a1b, a1bias,
                                                   a2b, a2bias, Wl, out);
}

// Round 21
// 62.382 us; speedup vs baseline: 1.0921x; 1.0921x over previous
//
#include <hip/hip_runtime.h>

#define NEG_SLOPE 0.1f

typedef _Float16 h4_t __attribute__((ext_vector_type(4)));
typedef _Float16 h8_t __attribute__((ext_vector_type(8)));
typedef float f32x4 __attribute__((ext_vector_type(4)));

__device__ __forceinline__ unsigned lds_off(const void* p) {
    return (unsigned)(unsigned long long)p;
}

__device__ __forceinline__ void lgkm0() {
    asm volatile("s_waitcnt lgkmcnt(0)" ::: "memory");
    __builtin_amdgcn_sched_barrier(0);        // rule #18
}

__device__ __forceinline__ h4_t tr16(unsigned addr) {
    h4_t d;
    asm volatile("ds_read_b64_tr_b16 %0, %1" : "=v"(d) : "v"(addr) : "memory");
    return d;
}

#define RCH 4

// ---------------------------------------------------------------------------
// K0 prep: W2T + wpack + WfT=(Wpca@W1)^T fp16 + x->fp16 + bfused + out init.
// blocks: [0,1024) W2T | [1024,3328) wpack | [3328,4352) WfT |
//         [4352,6400) x16 | 6400 bfused | [6401,6417) out-init.
// (Round-19 proven build, restored: the fp32-direct K1 A-staging of round 20
//  regressed — reg-staged conversion doubled x re-read traffic.)
// ---------------------------------------------------------------------------
__global__ __launch_bounds__(256) void prep2(const float* __restrict__ W2,
                                             const float* __restrict__ W1,
                                             const float* __restrict__ Wpca,
                                             const float* __restrict__ bpca,
                                             const float* __restrict__ b1,
                                             const float* __restrict__ a1W,
                                             const float* __restrict__ a2W,
                                             const float* __restrict__ Wp2,
                                             const float* __restrict__ x,
                                             const float* __restrict__ bp2,
                                             const float* __restrict__ Wl,
                                             const float* __restrict__ bl,
                                             _Float16* __restrict__ W2T,
                                             _Float16* __restrict__ wpack,
                                             _Float16* __restrict__ WfT,
                                             _Float16* __restrict__ x16,
                                             float* __restrict__ bfused,
                                             float* __restrict__ out)
{
    __shared__ alignas(16) char smem[17408];
    const int b   = blockIdx.x;
    const int tid = threadIdx.x;

    if (b < 1024) {                         // W2T[n][k] = fp16 W2[k][n]
        float (*tile)[33] = reinterpret_cast<float(*)[33]>(smem);
        const int n0 = (b & 31) * 32, k0 = (b >> 5) * 32;
        const int r = tid >> 3, c4 = (tid & 7) * 4;
        float4 v = *reinterpret_cast<const float4*>(&W2[(size_t)(k0 + r) * 1024 + n0 + c4]);
        tile[r][c4 + 0] = v.x; tile[r][c4 + 1] = v.y;
        tile[r][c4 + 2] = v.z; tile[r][c4 + 3] = v.w;
        __syncthreads();
        h4_t o;
        o[0] = (_Float16)tile[c4 + 0][r]; o[1] = (_Float16)tile[c4 + 1][r];
        o[2] = (_Float16)tile[c4 + 2][r]; o[3] = (_Float16)tile[c4 + 3][r];
        *reinterpret_cast<h4_t*>(&W2T[(size_t)(n0 + r) * 1024 + k0 + c4]) = o;
    } else if (b < 3328) {                  // pack tail weights (K=32 B-frag)
        const int idx = (b - 1024) * 256 + tid;
        if (idx < 589824) {
            const int r = idx / 9216, qq = idx % 9216;
            float v;
            if (qq < 1024) {
                int nt = qq >> 8, rem = qq & 255, l = rem >> 2, j = rem & 3;
                int n = nt * 16 + (l & 15), k = (l >> 4) * 4 + j;
                v = a1W[(size_t)r * 1024 + k * 64 + n];
            } else if (qq < 5120) {
                int p = qq - 1024, kt = p >> 11, u = p & 2047, nt = u >> 9, s = u & 511,
                    l = s >> 3, j = s & 7;
                int n = nt * 16 + (l & 15), k = kt * 32 + (l >> 4) * 8 + j;
                v = a2W[(size_t)r * 4096 + k * 64 + n];
            } else {
                int p = qq - 5120, kt = p >> 11, u = p & 2047, nt = u >> 9, s = u & 511,
                    l = s >> 3, j = s & 7;
                int n = nt * 16 + (l & 15), k = kt * 32 + (l >> 4) * 8 + j;
                v = Wp2[((size_t)r * 64 + k) * 64 + n];
            }
            wpack[idx] = (_Float16)v;
        }
    } else if (b < 4352) {                  // WfT[n][k] = fp16 sum_j Wpca[k][j]W1[j][n]
        float (*Ws)[65]  = reinterpret_cast<float(*)[65]>(smem);          // Wpca rows
        float (*W1s)[33] = reinterpret_cast<float(*)[33]>(smem + 8448);   // W1 cols
        const int b3 = b - 3328;
        const int n0 = (b3 & 31) * 32, k0 = (b3 >> 5) * 32;
        {
            const int r  = tid >> 3;            // 0..31
            const int j0 = (tid & 7) * 8;
            float4 v0 = *reinterpret_cast<const float4*>(&Wpca[(size_t)(k0 + r) * 64 + j0]);
            float4 v1 = *reinterpret_cast<const float4*>(&Wpca[(size_t)(k0 + r) * 64 + j0 + 4]);
            Ws[r][j0 + 0] = v0.x; Ws[r][j0 + 1] = v0.y; Ws[r][j0 + 2] = v0.z; Ws[r][j0 + 3] = v0.w;
            Ws[r][j0 + 4] = v1.x; Ws[r][j0 + 5] = v1.y; Ws[r][j0 + 6] = v1.z; Ws[r][j0 + 7] = v1.w;
            const int j  = tid >> 2;            // 0..63
            const int nq = (tid & 3) * 8;
            float4 w0 = *reinterpret_cast<const float4*>(&W1[(size_t)j * 1024 + n0 + nq]);
            float4 w1 = *reinterpret_cast<const float4*>(&W1[(size_t)j * 1024 + n0 + nq + 4]);
            W1s[j][nq + 0] = w0.x; W1s[j][nq + 1] = w0.y; W1s[j][nq + 2] = w0.z; W1s[j][nq + 3] = w0.w;
            W1s[j][nq + 4] = w1.x; W1s[j][nq + 5] = w1.y; W1s[j][nq + 6] = w1.z; W1s[j][nq + 7] = w1.w;
        }
        __syncthreads();
        const int nl = tid >> 3;            // 0..31
        const int kq = (tid & 7) * 4;
        float acc[4] = {0.f, 0.f, 0.f, 0.f};
#pragma unroll
        for (int j = 0; j < 64; ++j) {
            float wv = W1s[j][nl];
#pragma unroll
            for (int kk = 0; kk < 4; ++kk)
                acc[kk] = fmaf(Ws[kq + kk][j], wv, acc[kk]);
        }
        h4_t pk;
        pk[0] = (_Float16)acc[0]; pk[1] = (_Float16)acc[1];
        pk[2] = (_Float16)acc[2]; pk[3] = (_Float16)acc[3];
        *reinterpret_cast<h4_t*>(&WfT[(size_t)(n0 + nl) * 1024 + k0 + kq]) = pk;
    } else if (b < 6400) {                  // x16 = fp16(x)
        const size_t base = (size_t)(b - 4352) * 2048 + (size_t)tid * 8;
        float4 v0 = *reinterpret_cast<const float4*>(&x[base]);
        float4 v1 = *reinterpret_cast<const float4*>(&x[base + 4]);
        h8_t o;
        o[0] = (_Float16)v0.x; o[1] = (_Float16)v0.y; o[2] = (_Float16)v0.z; o[3] = (_Float16)v0.w;
        o[4] = (_Float16)v1.x; o[5] = (_Float16)v1.y; o[6] = (_Float16)v1.z; o[7] = (_Float16)v1.w;
        *reinterpret_cast<h8_t*>(&x16[base]) = o;
    } else if (b == 6400) {                 // bfused[n] = b1[n] + sum_j bpca[j]W1[j][n]
        const int n = tid * 4;
        float a0 = b1[n], a1v = b1[n + 1], a2v = b1[n + 2], a3 = b1[n + 3];
#pragma unroll
        for (int j = 0; j < 64; ++j) {
            float bp = bpca[j];
            a0  = fmaf(bp, W1[(size_t)j * 1024 + n + 0], a0);
            a1v = fmaf(bp, W1[(size_t)j * 1024 + n + 1], a1v);
            a2v = fmaf(bp, W1[(size_t)j * 1024 + n + 2], a2v);
            a3  = fmaf(bp, W1[(size_t)j * 1024 + n + 3], a3);
        }
        float4 o; o.x = a0; o.y = a1v; o.z = a2v; o.w = a3;
        *reinterpret_cast<float4*>(&bfused[n]) = o;
    } else {                                // out init with constant term
        const int idx = (b - 6401) * 256 + tid;
        float cst = bl[0];
#pragma unroll
        for (int f = 0; f < 64; ++f)
            cst += bp2[f] * Wl[f];
        out[idx] = cst;
    }
}

// ---------------------------------------------------------------------------
// K1: h1h = leaky(x16 @ Wf + bfused), LINEAR fp16 output.
// BM=64, BN=128, BK=64, grid (8,64) — proven v2 structure.
// ---------------------------------------------------------------------------
__global__ __launch_bounds__(256) void gemm_h1(const _Float16* __restrict__ A,
                                               const _Float16* __restrict__ BT,
                                               const float* __restrict__ bias,
                                               _Float16* __restrict__ C)
{
    __shared__ alignas(16) _Float16 As[64 * 64];
    __shared__ alignas(16) _Float16 Bs[128 * 64];
    const int tid = threadIdx.x;
    const int l   = tid & 63;
    const int w   = tid >> 6;
    const int wm  = w >> 1;
    const int wn  = w & 1;
    const int bm0 = blockIdx.y * 64;
    const int bn0 = blockIdx.x * 128;
    const int fr  = l & 15;
    const int fg  = l >> 4;
    const int srow  = l >> 3;
    const int sslot = l & 7;

    f32x4 acc[2][4] = {};

    for (int k0 = 0; k0 < 1024; k0 += 64) {
#pragma unroll
        for (int i = 0; i < 2; ++i) {
            const int r0   = w * 16 + i * 8;
            const int rowA = r0 + srow;
            const int slot = sslot ^ (rowA & 7);
            __builtin_amdgcn_global_load_lds(
                (const __attribute__((address_space(1))) void*)&A[(size_t)(bm0 + rowA) * 1024 + k0 + slot * 8],
                (__attribute__((address_space(3))) void*)&As[r0 * 64], 16, 0, 0);
        }
#pragma unroll
        for (int i = 0; i < 4; ++i) {
            const int r0   = w * 32 + i * 8;
            const int rowB = r0 + srow;
            const int slot = sslot ^ (rowB & 7);
            __builtin_amdgcn_global_load_lds(
                (const __attribute__((address_space(1))) void*)&BT[(size_t)(bn0 + rowB) * 1024 + k0 + slot * 8],
                (__attribute__((address_space(3))) void*)&Bs[r0 * 64], 16, 0, 0);
        }
        __syncthreads();

#pragma unroll
        for (int ks = 0; ks < 2; ++ks) {
            h8_t af[2], bf[4];
#pragma unroll
            for (int mt = 0; mt < 2; ++mt) {
                int row = wm * 32 + mt * 16 + fr;
                int sg  = ks * 4 + fg;
                af[mt] = *reinterpret_cast<const h8_t*>(&As[row * 64 + ((sg ^ (row & 7)) << 3)]);
            }
#pragma unroll
            for (int nt = 0; nt < 4; ++nt) {
                int row = wn * 64 + nt * 16 + fr;
                int sg  = ks * 4 + fg;
                bf[nt] = *reinterpret_cast<const h8_t*>(&Bs[row * 64 + ((sg ^ (row & 7)) << 3)]);
            }
#pragma unroll
            for (int mt = 0; mt < 2; ++mt)
#pragma unroll
                for (int nt = 0; nt < 4; ++nt)
                    acc[mt][nt] = __builtin_amdgcn_mfma_f32_16x16x32_f16(af[mt], bf[nt],
                                                                         acc[mt][nt], 0, 0, 0);
        }
        __syncthreads();
    }

#pragma unroll
    for (int nt = 0; nt < 4; ++nt) {
        const int col = bn0 + wn * 64 + nt * 16 + fr;
        const float bv = bias[col];
#pragma unroll
        for (int mt = 0; mt < 2; ++mt)
#pragma unroll
            for (int rg = 0; rg < 4; ++rg) {
                const int row = bm0 + wm * 32 + mt * 16 + fg * 4 + rg;
                float v = acc[mt][nt][rg] + bv;
                C[(size_t)row * 1024 + col] = (_Float16)fmaxf(v, NEG_SLOPE * v);
            }
    }
}

// ---------------------------------------------------------------------------
// K2: h2t = pack(leaky(h1 @ W2 + b2)). (unchanged proven v2)
// ---------------------------------------------------------------------------
__global__ __launch_bounds__(256) void gemm_mfma_f16_v2(const _Float16* __restrict__ A,
                                                        const _Float16* __restrict__ BT,
                                                        const float* __restrict__ bias,
                                                        _Float16* __restrict__ h2t)
{
    __shared__ alignas(16) _Float16 As[64 * 64];
    __shared__ alignas(16) _Float16 Bs[128 * 64];
    const int tid = threadIdx.x;
    const int l   = tid & 63;
    const int w   = tid >> 6;
    const int wm  = w >> 1;
    const int wn  = w & 1;
    const int bm0 = blockIdx.y * 64;
    const int bn0 = blockIdx.x * 128;
    const int fr  = l & 15;
    const int fg  = l >> 4;
    const int srow  = l >> 3;
    const int sslot = l & 7;

    f32x4 acc[2][4] = {};

    for (int k0 = 0; k0 < 1024; k0 += 64) {
#pragma unroll
        for (int i = 0; i < 2; ++i) {
            const int r0   = w * 16 + i * 8;
            const int rowA = r0 + srow;
            const int slot = sslot ^ (rowA & 7);
            __builtin_amdgcn_global_load_lds(
                (const __attribute__((address_space(1))) void*)&A[(size_t)(bm0 + rowA) * 1024 + k0 + slot * 8],
                (__attribute__((address_space(3))) void*)&As[r0 * 64], 16, 0, 0);
        }
#pragma unroll
        for (int i = 0; i < 4; ++i) {
            const int r0   = w * 32 + i * 8;
            const int rowB = r0 + srow;
            const int slot = sslot ^ (rowB & 7);
            __builtin_amdgcn_global_load_lds(
                (const __attribute__((address_space(1))) void*)&BT[(size_t)(bn0 + rowB) * 1024 + k0 + slot * 8],
                (__attribute__((address_space(3))) void*)&Bs[r0 * 64], 16, 0, 0);
        }
        __syncthreads();

#pragma unroll
        for (int ks = 0; ks < 2; ++ks) {
            h8_t af[2], bf[4];
#pragma unroll
            for (int mt = 0; mt < 2; ++mt) {
                int row = wm * 32 + mt * 16 + fr;
                int sg  = ks * 4 + fg;
                af[mt] = *reinterpret_cast<const h8_t*>(&As[row * 64 + ((sg ^ (row & 7)) << 3)]);
            }
#pragma unroll
            for (int nt = 0; nt < 4; ++nt) {
                int row = wn * 64 + nt * 16 + fr;
                int sg  = ks * 4 + fg;
                bf[nt] = *reinterpret_cast<const h8_t*>(&Bs[row * 64 + ((sg ^ (row & 7)) << 3)]);
            }
#pragma unroll
            for (int mt = 0; mt < 2; ++mt)
#pragma unroll
                for (int nt = 0; nt < 4; ++nt)
                    acc[mt][nt] = __builtin_amdgcn_mfma_f32_16x16x32_f16(af[mt], bf[nt],
                                                                         acc[mt][nt], 0, 0, 0);
        }
        __syncthreads();
    }

    const int rblk0 = (bm0 >> 4) + wm * 2;
    const int cblk0 = (bn0 >> 4) + wn * 4;
#pragma unroll
    for (int nt = 0; nt < 4; ++nt) {
        const int col = bn0 + wn * 64 + nt * 16 + fr;
        const float bv = bias[col];
#pragma unroll
        for (int mt = 0; mt < 2; ++mt) {
            h4_t pk;
#pragma unroll
            for (int r = 0; r < 4; ++r) {
                float v = acc[mt][nt][r] + bv;
                pk[r] = (_Float16)fmaxf(v, NEG_SLOPE * v);
            }
            *reinterpret_cast<h4_t*>(
                &h2t[(((size_t)(cblk0 + nt) * 256 + rblk0 + mt) * 16 + fr) * 16 + fg * 4]) = pk;
        }
    }
}

// ---------------------------------------------------------------------------
// K3: fused additive chain v5b (unchanged from passing round 19).
// ---------------------------------------------------------------------------
__global__ __launch_bounds__(256) void fused_tail5b(const _Float16* __restrict__ h2t,
                                                    const _Float16* __restrict__ wpack,
                                                    const float* __restrict__ a1b,
                                                    const float* __restrict__ a1bias,
                                                    const float* __restrict__ a2b,
                                                    const float* __restrict__ a2bias,
                                                    const float* __restrict__ Wl,
                                                    float* __restrict__ out)
{
    __shared__ alignas(16) _Float16 stage[2][11264];  // 2 x 22KB
    __shared__ alignas(16) _Float16 act[4][2048];     // per-wave, 2 tiles (16KB)

    const int tid = threadIdx.x;
    const int l = tid & 63, w = tid >> 6;
    const int c = l & 15, q = l >> 4;
    const int row0  = blockIdx.x * 128;
    const int rbase = blockIdx.y * RCH;
    const float b1s = a1bias[0], b2s = a2bias[0];

    const unsigned trl   = l * 8;
    const unsigned abase = lds_off(&act[w][0]);

    float b1v[RCH][4], b2v[RCH][4];
#pragma unroll
    for (int rl = 0; rl < RCH; ++rl)
#pragma unroll
        for (int nt = 0; nt < 4; ++nt) {
            b1v[rl][nt] = a1b[(rbase + rl) * 64 + nt * 16 + c] + b1s;
            b2v[rl][nt] = a2b[(rbase + rl) * 64 + nt * 16 + c] + b2s;
        }
    float wlv[4];
#pragma unroll
    for (int nt = 0; nt < 4; ++nt) wlv[nt] = Wl[nt * 16 + c];

    auto STAGE = [&](int rl, int b) {
        const int r = rbase + rl;
        const _Float16* hsrc = h2t + ((size_t)r * 256 + blockIdx.x * 8) * 256;
        const _Float16* wsrc = wpack + (size_t)r * 9216;
#pragma unroll
        for (int i = 0; i < 6; ++i) {
            const int ch = i * 4 + w;
            if (ch < 22) {
                const _Float16* src = (ch < 4) ? (hsrc + ch * 512) : (wsrc + (ch - 4) * 512);
                __builtin_amdgcn_global_load_lds(
                    (const __attribute__((address_space(1))) void*)(src + l * 8),
                    (__attribute__((address_space(3))) void*)&stage[b][ch * 512], 16, 0, 0);
            }
        }
    };

    STAGE(0, 0);
    __syncthreads();

    f32x4 accT[2][4] = {};
    int cur = 0;

#pragma unroll
    for (int rl = 0; rl < RCH; ++rl) {
        if (rl + 1 < RCH) STAGE(rl + 1, cur ^ 1);

        const _Float16* sp = &stage[cur][0];
        const unsigned sbytes = lds_off(sp);

        // ---- phase A
        h4_t ha0 = tr16(sbytes + (unsigned)(w) * 512 + trl);
        h4_t ha1 = tr16(sbytes + (unsigned)(w + 4) * 512 + trl);
        lgkm0();
        f32x4 pa[2][4];
#pragma unroll
        for (int nt = 0; nt < 4; ++nt) {
            h4_t bf = *reinterpret_cast<const h4_t*>(&sp[2048 + nt * 256 + l * 4]);
            pa[0][nt] = __builtin_amdgcn_mfma_f32_16x16x16f16(ha0, bf, (f32x4){0.f,0.f,0.f,0.f}, 0, 0, 0);
            pa[1][nt] = __builtin_amdgcn_mfma_f32_16x16x16f16(ha1, bf, (f32x4){0.f,0.f,0.f,0.f}, 0, 0, 0);
        }
#pragma unroll
        for (int j = 0; j < 2; ++j)
#pragma unroll
            for (int nt = 0; nt < 4; ++nt) {
                h4_t pk;
#pragma unroll
                for (int rg = 0; rg < 4; ++rg) {
                    float v = pa[j][nt][rg] + b1v[rl][nt];
                    pk[rg] = (_Float16)fmaxf(v, NEG_SLOPE * v);
                }
                const int kk = nt * 16 + c;
                const int hh = (kk >> 2) & 1;
                const int kp = (kk & 3) | ((kk >> 3) << 2);
                *reinterpret_cast<h4_t*>(&act[w][j * 1024 + hh * 512 + kp * 16 + q * 4]) = pk;
            }
        lgkm0();

        // ---- phase B
        h8_t afB[2][2];
#pragma unroll
        for (int j = 0; j < 2; ++j)
#pragma unroll
            for (int kt = 0; kt < 2; ++kt) {
                h4_t lo = tr16(abase + (unsigned)(j * 2048 + kt * 512) + trl);
                h4_t hi = tr16(abase + (unsigned)(j * 2048 + 1024 + kt * 512) + trl);
                afB[j][kt] = __builtin_shufflevector(lo, hi, 0, 1, 2, 3, 4, 5, 6, 7);
            }
        lgkm0();
        f32x4 pb[2][4] = {};
#pragma unroll
        for (int kt = 0; kt < 2; ++kt)
#pragma unroll
            for (int nt = 0; nt < 4; ++nt) {
                h8_t bf = *reinterpret_cast<const h8_t*>(&sp[3072 + kt * 2048 + nt * 512 + l * 8]);
                pb[0][nt] = __builtin_amdgcn_mfma_f32_16x16x32_f16(afB[0][kt], bf, pb[0][nt], 0, 0, 0);
                pb[1][nt] = __builtin_amdgcn_mfma_f32_16x16x32_f16(afB[1][kt], bf, pb[1][nt], 0, 0, 0);
            }
#pragma unroll
        for (int j = 0; j < 2; ++j)
#pragma unroll
            for (int nt = 0; nt < 4; ++nt) {
                h4_t pk;
#pragma unroll
                for (int rg = 0; rg < 4; ++rg) {
                    float v = pb[j][nt][rg] + b2v[rl][nt];
                    pk[rg] = (_Float16)fmaxf(v, NEG_SLOPE * v);
                }
                const int kk = nt * 16 + c;
                const int hh = (kk >> 2) & 1;
                const int kp = (kk & 3) | ((kk >> 3) << 2);
                *reinterpret_cast<h4_t*>(&act[w][j * 1024 + hh * 512 + kp * 16 + q * 4]) = pk;
            }
        lgkm0();

        // ---- phase C
        h8_t afC[2][2];
#pragma unroll
        for (int j = 0; j < 2; ++j)
#pragma unroll
            for (int kt = 0; kt < 2; ++kt) {
                h4_t lo = tr16(abase + (unsigned)(j * 2048 + kt * 512) + trl);
                h4_t hi = tr16(abase + (unsigned)(j * 2048 + 1024 + kt * 512) + trl);
                afC[j][kt] = __builtin_shufflevector(lo, hi, 0, 1, 2, 3, 4, 5, 6, 7);
            }
        lgkm0();
#pragma unroll
        for (int kt = 0; kt < 2; ++kt)
#pragma unroll
            for (int nt = 0; nt < 4; ++nt) {
                h8_t bf = *reinterpret_cast<const h8_t*>(&sp[7168 + kt * 2048 + nt * 512 + l * 8]);
                accT[0][nt] = __builtin_amdgcn_mfma_f32_16x16x32_f16(afC[0][kt], bf, accT[0][nt], 0, 0, 0);
                accT[1][nt] = __builtin_amdgcn_mfma_f32_16x16x32_f16(afC[1][kt], bf, accT[1][nt], 0, 0, 0);
            }

        __syncthreads();
        cur ^= 1;
    }

    // ---- epilogue: per-row dot with Wl, lane-reduce, atomicAdd
#pragma unroll
    for (int j = 0; j < 2; ++j)
#pragma unroll
        for (int rg = 0; rg < 4; ++rg) {
            float s = accT[j][0][rg] * wlv[0] + accT[j][1][rg] * wlv[1] +
                      accT[j][2][rg] * wlv[2] + accT[j][3][rg] * wlv[3];
            s += __shfl_xor(s, 1);
            s += __shfl_xor(s, 2);
            s += __shfl_xor(s, 4);
            s += __shfl_xor(s, 8);
            if (c == 0) {
                const int row = row0 + (w + 4 * j) * 16 + q * 4 + rg;
                atomicAdd(&out[row], s);
            }
        }
}

// ---------------------------------------------------------------------------
extern "C" void kernel_launch(void* const* d_in, const int* in_sizes, int n_in,
                              void* d_out, int out_size, void* d_ws, size_t ws_size,
                              hipStream_t stream)
{
    const float* x      = (const float*)d_in[0];
    const float* Wpca   = (const float*)d_in[1];
    const float* bpca   = (const float*)d_in[2];
    const float* W1     = (const float*)d_in[3];
    const float* b1     = (const float*)d_in[4];
    const float* W2     = (const float*)d_in[5];
    const float* b2     = (const float*)d_in[6];
    const float* a1W    = (const float*)d_in[7];
    const float* a1b    = (const float*)d_in[8];
    const float* a1bias = (const float*)d_in[9];
    const float* a2W    = (const float*)d_in[10];
    const float* a2b    = (const float*)d_in[11];
    const float* a2bias = (const float*)d_in[12];
    const float* Wp2    = (const float*)d_in[13];
    const float* bp2    = (const float*)d_in[14];
    const float* Wl     = (const float*)d_in[15];
    const float* bl     = (const float*)d_in[16];
    float* out = (float*)d_out;

    // workspace layout (bytes) — fully disjoint:
    //   x16 [0,8M)  h1h [8M,16M)  h2t [16M,24M)  W2T [24M,26M)
    //   wpack [26M,27.13M)  WfT [28M,30M)  bfused [30.5M,+4KB)
    char* wsb = (char*)d_ws;
    _Float16* x16    = (_Float16*)(wsb);
    _Float16* h1h    = (_Float16*)(wsb + (8ull  << 20));
    _Float16* h2t    = (_Float16*)(wsb + (16ull << 20));
    _Float16* W2T    = (_Float16*)(wsb + (24ull << 20));
    _Float16* wpack  = (_Float16*)(wsb + (26ull << 20));
    _Float16* WfT    = (_Float16*)(wsb + (28ull << 20));
    float*    bfused = (float*)   (wsb + (30ull << 20) + (512ull << 10));

    // K0: all prep in one launch (W2T || wpack || WfT || x16 || bfused || out)
    prep2<<<dim3(6417), 256, 0, stream>>>(W2, W1, Wpca, bpca, b1, a1W, a2W, Wp2,
                                          x, bp2, Wl, bl,
                                          W2T, wpack, WfT, x16, bfused, out);
    // K1: h1 = leaky(x @ (Wpca@W1) + bfused)  — fused PCA1+NN1, MFMA
    gemm_h1<<<dim3(8, 64), 256, 0, stream>>>(x16, WfT, bfused, h1h);
    // K2: h2 (packed) = leaky(h1 @ W2 + b2) via MFMA
    gemm_mfma_f16_v2<<<dim3(8, 64), 256, 0, stream>>>(h1h, W2T, b2, h2t);
    // K3: fused additive chain -> atomicAdd into out
    fused_tail5b<<<dim3(32, 16), 256, 0, stream>>>(h2t, wpack, a1b, a1bias,
                                                   a2b, a2bias, Wl, out);
}